// Round 13
// baseline (266.519 us; speedup 1.0000x reference)
//
#include <hip/hip_runtime.h>
#include <hip/hip_bf16.h>

// RNN-T Joiner. N=8 T=512 U=64 J=512 V=500 (padded 512).
// ws: enc_p bf16 [4096,512] | dec_p bf16 [512,512] | wimg bf16 frag-ordered (512KB) | bpad
// prep (273 blocks): conv_wout (128) | enc proj (128) | dec proj (16) | bpad (1)
// joiner: 8192 blocks x 256 thr (4 waves). Block = (n, t, vt half of V). BM=64, BN=256,
//   BK=32, wave 64m x 64v, mfma 32x32x16, B global->regs (1-kt reg prefetch),
//   lgkm-only barriers. 4 blocks/CU (LDS 24.8KB, VGPR<=128) -> 4 independent
//   barrier domains per CU so store drains overlap other blocks' k-loops.

typedef __attribute__((ext_vector_type(4))) float f32x4;
typedef __attribute__((ext_vector_type(16))) float f32x16;
typedef __attribute__((ext_vector_type(4))) short s16x4;
typedef __attribute__((ext_vector_type(8))) short s16x8;
typedef __attribute__((ext_vector_type(8))) unsigned short u16x8;

static __device__ __forceinline__ unsigned short f2bf(float x) {
    union { float f; unsigned u; } v; v.f = x;
    return (unsigned short)((v.u + 0x7FFFu + ((v.u >> 16) & 1u)) >> 16);  // RNE
}

static __device__ __forceinline__ float bf2f(unsigned short u) {
    union { unsigned u; float f; } v; v.u = ((unsigned)u) << 16;
    return v.f;
}

static __device__ __forceinline__ float fast_tanh(float x) {
    float e = __expf(2.0f * x);
    float r = __builtin_amdgcn_rcpf(e + 1.0f);
    return __builtin_fmaf(-2.0f, r, 1.0f);
}

// lgkm-only barrier (R10/R11-verified): orders LDS cross-wave, never drains vmcnt.
static __device__ __forceinline__ void lbar() {
    asm volatile("s_waitcnt lgkmcnt(0)" ::: "memory");
    __builtin_amdgcn_s_barrier();
    __builtin_amdgcn_sched_barrier(0);
}

// 64B-row swizzle: row r, 16B-slot c; byte = r*64 + ((c ^ ((r>>1)&3)) << 4)
static __device__ __forceinline__ unsigned swz64(int r, int c) {
    return (unsigned)(r * 64 + ((c ^ ((r >> 1) & 3)) << 4));
}

// ---------------- projection GEMM body (verified; bf16 output) ----------------
static __device__ void proj_body(
    const float* __restrict__ A, const float* __restrict__ W,
    const float* __restrict__ b, unsigned short* __restrict__ C,
    int mt, int jt, unsigned short* As, unsigned short* Bs)
{
    const int tid = threadIdx.x;
    const int lane = tid & 63, wid = tid >> 6;
    const int wm = wid >> 1, wn = wid & 1;

    f32x4 acc[4][4];
    const f32x4 zero = {0.f, 0.f, 0.f, 0.f};
    #pragma unroll
    for (int i = 0; i < 4; ++i)
        #pragma unroll
        for (int j = 0; j < 4; ++j) acc[i][j] = zero;

    const int c8 = (tid & 7) * 8;
    const int rbase = tid >> 3;

    for (int kt = 0; kt < 8; ++kt) {
        __syncthreads();
        #pragma unroll
        for (int p = 0; p < 4; ++p) {
            int r = p * 32 + rbase;
            int byte = (r * 128 + c8 * 2) ^ ((r & 7) << 4);
            {
                const float* s = A + (size_t)(mt * 128 + r) * 512 + kt * 64 + c8;
                f32x4 v0 = *(const f32x4*)s, v1 = *(const f32x4*)(s + 4);
                s16x8 pk;
                pk[0] = (short)f2bf(v0[0]); pk[1] = (short)f2bf(v0[1]);
                pk[2] = (short)f2bf(v0[2]); pk[3] = (short)f2bf(v0[3]);
                pk[4] = (short)f2bf(v1[0]); pk[5] = (short)f2bf(v1[1]);
                pk[6] = (short)f2bf(v1[2]); pk[7] = (short)f2bf(v1[3]);
                *(s16x8*)((char*)As + byte) = pk;
            }
            {
                const float* s = W + (size_t)(jt * 128 + r) * 512 + kt * 64 + c8;
                f32x4 v0 = *(const f32x4*)s, v1 = *(const f32x4*)(s + 4);
                s16x8 pk;
                pk[0] = (short)f2bf(v0[0]); pk[1] = (short)f2bf(v0[1]);
                pk[2] = (short)f2bf(v0[2]); pk[3] = (short)f2bf(v0[3]);
                pk[4] = (short)f2bf(v1[0]); pk[5] = (short)f2bf(v1[1]);
                pk[6] = (short)f2bf(v1[2]); pk[7] = (short)f2bf(v1[3]);
                *(s16x8*)((char*)Bs + byte) = pk;
            }
        }
        __syncthreads();
        #pragma unroll
        for (int kk = 0; kk < 2; ++kk) {
            s16x8 af[4], bfr[4];
            #pragma unroll
            for (int mi = 0; mi < 4; ++mi) {
                int row = wm * 64 + mi * 16 + (lane & 15);
                int byte = (row * 128 + kk * 64 + ((lane >> 4) * 16)) ^ ((row & 7) << 4);
                af[mi] = *(const s16x8*)((const char*)As + byte);
            }
            #pragma unroll
            for (int ni = 0; ni < 4; ++ni) {
                int row = wn * 64 + ni * 16 + (lane & 15);
                int byte = (row * 128 + kk * 64 + ((lane >> 4) * 16)) ^ ((row & 7) << 4);
                bfr[ni] = *(const s16x8*)((const char*)Bs + byte);
            }
            #pragma unroll
            for (int mi = 0; mi < 4; ++mi)
                #pragma unroll
                for (int ni = 0; ni < 4; ++ni)
                    acc[mi][ni] = __builtin_amdgcn_mfma_f32_16x16x32_bf16(
                        af[mi], bfr[ni], acc[mi][ni], 0, 0, 0);
        }
    }

    #pragma unroll
    for (int ni = 0; ni < 4; ++ni) {
        int col = jt * 128 + wn * 64 + ni * 16 + (lane & 15);
        float bias = b[col];
        #pragma unroll
        for (int mi = 0; mi < 4; ++mi) {
            int row0 = mt * 128 + wm * 64 + mi * 16 + ((lane >> 4) << 2);
            #pragma unroll
            for (int j = 0; j < 4; ++j)
                C[(size_t)(row0 + j) * 512 + col] = f2bf(acc[mi][ni][j] + bias);
        }
    }
}

// ---------------- fused prep: conv_wout | enc proj | dec proj | bpad ----------------
__global__ __launch_bounds__(256) void prep(
    const float* __restrict__ Wout, unsigned short* __restrict__ img,
    const float* __restrict__ encoder_out, const float* __restrict__ W_enc,
    const float* __restrict__ b_enc, unsigned short* __restrict__ enc_p,
    const float* __restrict__ decoder_out, const float* __restrict__ W_dec,
    const float* __restrict__ b_dec, unsigned short* __restrict__ dec_p,
    const float* __restrict__ b_out, float* __restrict__ bpad)
{
    __shared__ unsigned short As[128 * 64];
    __shared__ unsigned short Bs[128 * 64];
    const int b = blockIdx.x;
    if (b < 128) {
        // W_out -> bf16 per-lane MFMA-fragment-ordered image (verified layout):
        // chunk tid = ((kt*16+tile)*2+khalf)*64+lane -> 8 bf16 of
        //   W[v=tile*32+(lane&31)][k=kt*32+khalf*16+(lane>>5)*8 + j], v>=500 -> 0
        int tid = b * 256 + threadIdx.x;
        int lane = tid & 63;
        int khalf = (tid >> 6) & 1;
        int tile = (tid >> 7) & 15;
        int kt = tid >> 11;
        int v = tile * 32 + (lane & 31);
        int k = kt * 32 + khalf * 16 + (lane >> 5) * 8;
        s16x8 pk = {0, 0, 0, 0, 0, 0, 0, 0};
        if (v < 500) {
            const float* s = Wout + (size_t)v * 512 + k;
            f32x4 a = *(const f32x4*)s, c = *(const f32x4*)(s + 4);
            pk[0] = (short)f2bf(a[0]); pk[1] = (short)f2bf(a[1]);
            pk[2] = (short)f2bf(a[2]); pk[3] = (short)f2bf(a[3]);
            pk[4] = (short)f2bf(c[0]); pk[5] = (short)f2bf(c[1]);
            pk[6] = (short)f2bf(c[2]); pk[7] = (short)f2bf(c[3]);
        }
        *(s16x8*)(img + (size_t)tid * 8) = pk;
    } else if (b < 256) {
        int q = b - 128;                       // enc proj: M=4096
        proj_body(encoder_out, W_enc, b_enc, enc_p, q & 31, q >> 5, As, Bs);
    } else if (b < 272) {
        int q = b - 256;                       // dec proj: M=512
        proj_body(decoder_out, W_dec, b_dec, dec_p, q & 3, q >> 2, As, Bs);
    } else {
        int i = threadIdx.x;                   // bpad: 512-padded bias
        bpad[i] = (i < 500) ? b_out[i] : 0.f;
        bpad[i + 256] = (i + 256 < 500) ? b_out[i + 256] : 0.f;
    }
}

// ---------------- fused tanh + vocab GEMM ----------------
__global__ __launch_bounds__(256, 4) void joiner_main(
    const unsigned short* __restrict__ enc, const unsigned short* __restrict__ dec,
    const unsigned short* __restrict__ Wimg, const float* __restrict__ bout,
    float* __restrict__ out)
{
    __shared__ __align__(16) char raw[8192 + 16 * 260 * 4];   // A dbuf 8KB + ep [16][260]
    unsigned short* As0 = (unsigned short*)raw;               // 4 KB [64 r][32 k] swizzled
    unsigned short* As1 = (unsigned short*)(raw + 4096);
    float* ep = (float*)(raw + 8192);

    const int bid = blockIdx.x;                 // bid = (n*512 + t)*2 + vt
    const int tid = threadIdx.x, lane = tid & 63, wn = tid >> 6;  // 4 waves across 256 v
    const int vt = bid & 1, t = (bid >> 1) & 511, n = bid >> 10;

    f32x16 acc[2][2];
    #pragma unroll
    for (int i = 0; i < 2; ++i)
        #pragma unroll
        for (int j = 0; j < 2; ++j)
            #pragma unroll
            for (int e = 0; e < 16; ++e) acc[i][j][e] = 0.f;

    // A staging: thread -> row r = tid>>2 (u 0..63), 16B chunk q = tid&3 (k = q*8..+7)
    const int r = tid >> 2;
    const int q = tid & 3;
    const unsigned short* erow = enc + ((size_t)n * 512 + t) * 512 + q * 8;
    const unsigned short* drow = dec + ((size_t)n * 64 + r) * 512 + q * 8;
    const unsigned abyte = swz64(r, q);
    // B fragments: frag-ordered image; this block's v-window = vt*256; wave wn owns
    // v-tiles (vt*8 + wn*2) + {0,1}. Layout: kt*32768 + vtile*2048 + khalf*1024 + lane*16
    const char* wbase = (const char*)Wimg + (size_t)(vt * 8 + wn * 2) * 2048
                        + (size_t)lane * 16;
    const int lr = lane & 31, kg = lane >> 5;

    // ---- prologue: stage A(kt0); load B(kt0) into regs ----
    s16x8 bc0, bc1, bc2, bc3;
    {
        u16x8 e = *(const u16x8*)erow;
        u16x8 d = *(const u16x8*)drow;
        s16x8 p;
        #pragma unroll
        for (int i = 0; i < 8; ++i)
            p[i] = (short)f2bf(fast_tanh(bf2f(e[i]) + bf2f(d[i])));
        *(s16x8*)((char*)As0 + abyte) = p;
        bc0 = *(const s16x8*)(wbase);
        bc1 = *(const s16x8*)(wbase + 1024);
        bc2 = *(const s16x8*)(wbase + 2048);
        bc3 = *(const s16x8*)(wbase + 3072);
    }
    lbar();

    #pragma unroll
    for (int kt = 0; kt < 16; ++kt) {
        const char* Ac = (char*)((kt & 1) ? As1 : As0);
        char* An = (char*)((kt & 1) ? As0 : As1);

        // 1. issue e/d loads for kt+1 (consumed after the MFMAs -> latency hidden)
        u16x8 eL, dL;
        if (kt < 15) {
            eL = *(const u16x8*)(erow + (kt + 1) * 32);
            dL = *(const u16x8*)(drow + (kt + 1) * 32);
        }
        // 2. prefetch B(kt+1) into regs
        s16x8 bn0, bn1, bn2, bn3;
        if (kt < 15) {
            const char* g = wbase + (size_t)(kt + 1) * 32768;
            bn0 = *(const s16x8*)(g);
            bn1 = *(const s16x8*)(g + 1024);
            bn2 = *(const s16x8*)(g + 2048);
            bn3 = *(const s16x8*)(g + 3072);
        }
        // 3. A fragment reads + MFMA with current B regs
        {
            s16x8 a0 = *(const s16x8*)(Ac + swz64(lr, kg));
            s16x8 a1 = *(const s16x8*)(Ac + swz64(32 + lr, kg));
            acc[0][0] = __builtin_amdgcn_mfma_f32_32x32x16_bf16(bc0, a0, acc[0][0], 0, 0, 0);
            acc[0][1] = __builtin_amdgcn_mfma_f32_32x32x16_bf16(bc2, a0, acc[0][1], 0, 0, 0);
            acc[1][0] = __builtin_amdgcn_mfma_f32_32x32x16_bf16(bc0, a1, acc[1][0], 0, 0, 0);
            acc[1][1] = __builtin_amdgcn_mfma_f32_32x32x16_bf16(bc2, a1, acc[1][1], 0, 0, 0);
            a0 = *(const s16x8*)(Ac + swz64(lr, 2 + kg));
            a1 = *(const s16x8*)(Ac + swz64(32 + lr, 2 + kg));
            acc[0][0] = __builtin_amdgcn_mfma_f32_32x32x16_bf16(bc1, a0, acc[0][0], 0, 0, 0);
            acc[0][1] = __builtin_amdgcn_mfma_f32_32x32x16_bf16(bc3, a0, acc[0][1], 0, 0, 0);
            acc[1][0] = __builtin_amdgcn_mfma_f32_32x32x16_bf16(bc1, a1, acc[1][0], 0, 0, 0);
            acc[1][1] = __builtin_amdgcn_mfma_f32_32x32x16_bf16(bc3, a1, acc[1][1], 0, 0, 0);
        }
        // 4. tanh + stage A(kt+1) (e/d loads drained during MFMAs; VALU free here)
        if (kt < 15) {
            s16x8 p;
            #pragma unroll
            for (int i = 0; i < 8; ++i)
                p[i] = (short)f2bf(fast_tanh(bf2f(eL[i]) + bf2f(dL[i])));
            *(s16x8*)(An + abyte) = p;
        }
        // 5. lgkm-only barrier; B prefetch stays in flight
        lbar();
        bc0 = bn0; bc1 = bn1; bc2 = bn2; bc3 = bn3;
    }

    // ---- epilogue: 4 rounds of 16 rows; LDS transpose -> linear NT streams ----
    // acc[mi][ni][reg]: m = mi*32 + lr,
    //   v_local = wn*64 + ni*32 + (reg&3) + 8*(reg>>2) + 4*kg   (block window vt*256)
    const int hi4 = kg * 4;
    const size_t mg = ((size_t)n * 512 + t) * 64;
    #pragma unroll
    for (int o = 0; o < 4; ++o) {
        if (o) lbar();                    // round 0 covered by k-loop's final lbar
        if ((lr >> 4) == (o & 1)) {
            const int mi = o >> 1;
            const int lrow = lr & 15;
            #pragma unroll
            for (int ni = 0; ni < 2; ++ni) {
                #pragma unroll
                for (int qq = 0; qq < 4; ++qq) {
                    int vloc = wn * 64 + ni * 32 + qq * 8 + hi4;
                    int v4 = vt * 256 + vloc;
                    if (v4 < 500) {
                        f32x4 b = *(const f32x4*)(bout + v4);   // bout 512-padded
                        f32x4 ov;
                        ov[0] = acc[mi][ni][qq * 4 + 0] + b[0];
                        ov[1] = acc[mi][ni][qq * 4 + 1] + b[1];
                        ov[2] = acc[mi][ni][qq * 4 + 2] + b[2];
                        ov[3] = acc[mi][ni][qq * 4 + 3] + b[3];
                        *(f32x4*)(ep + lrow * 260 + vloc) = ov;
                    }
                }
            }
        }
        lbar();
        const int row0 = (o >> 1) * 32 + (o & 1) * 16;
        #pragma unroll
        for (int i = 0; i < 4; ++i) {
            int idx = i * 256 + tid;                 // 16 rows x 64 chunks = 1024
            int rr = idx >> 6, ci = idx & 63;
            int v4 = vt * 256 + ci * 4;
            if (v4 < 500) {
                f32x4 ov = *(const f32x4*)(ep + rr * 260 + ci * 4);
                __builtin_nontemporal_store(
                    ov, (f32x4*)(out + (mg + row0 + rr) * 500 + v4));
            }
        }
    }
}

extern "C" void kernel_launch(void* const* d_in, const int* in_sizes, int n_in,
                              void* d_out, int out_size, void* d_ws, size_t ws_size,
                              hipStream_t stream) {
    const float* encoder_out = (const float*)d_in[0];  // [8,512,512]
    const float* decoder_out = (const float*)d_in[1];  // [8,64,512]
    const float* W_enc = (const float*)d_in[2];
    const float* b_enc = (const float*)d_in[3];
    const float* W_dec = (const float*)d_in[4];
    const float* b_dec = (const float*)d_in[5];
    const float* W_out = (const float*)d_in[6];        // [500,512]
    const float* b_out = (const float*)d_in[7];        // [500]
    float* out = (float*)d_out;                        // [8,512,64,500]

    unsigned short* enc_p = (unsigned short*)d_ws;              // 4 MB bf16
    unsigned short* dec_p = enc_p + (size_t)4096 * 512;         // 512 KB bf16
    unsigned short* wimg  = dec_p + (size_t)512 * 512;          // 512 KB bf16
    float* bpad = (float*)(wimg + 262144);                      // 2 KB f32

    prep<<<dim3(273), 256, 0, stream>>>(W_out, wimg,
                                        encoder_out, W_enc, b_enc, enc_p,
                                        decoder_out, W_dec, b_dec, dec_p,
                                        b_out, bpad);
    joiner_main<<<dim3(8192), 256, 0, stream>>>(enc_p, dec_p, wimg, bpad, out);
}

// Round 14
// 214.600 us; speedup vs baseline: 1.2419x; 1.2419x over previous
//
#include <hip/hip_runtime.h>
#include <hip/hip_bf16.h>

// RNN-T Joiner. N=8 T=512 U=64 J=512 V=500 (padded 512).
// ws: enc_p bf16 [4096,512] | dec_p bf16 [512,512] | wimg bf16 frag-ordered (512KB) | bpad
// prep (273 blocks): conv_wout (128) | enc proj (128) | dec proj (16) | bpad (1)
// joiner: 2048 blocks x 512 thr (8 waves). BM=128 (2t x 64u), BN=512, BK=32.
//   WAVE TILE 128m x 64v (acc[4][2]) -> B L1 traffic HALVED vs 64m tiles (B was the
//   bottleneck: 1024 cyc/kt of L1 load BW vs 256 cyc MFMA). B global->regs, 1-kt
//   prefetch; lgkm-only barriers; 1 block/CU (VGPR ~245, launch_bounds(512,2)).

typedef __attribute__((ext_vector_type(4))) float f32x4;
typedef __attribute__((ext_vector_type(16))) float f32x16;
typedef __attribute__((ext_vector_type(8))) short s16x8;
typedef __attribute__((ext_vector_type(8))) unsigned short u16x8;

static __device__ __forceinline__ unsigned short f2bf(float x) {
    union { float f; unsigned u; } v; v.f = x;
    return (unsigned short)((v.u + 0x7FFFu + ((v.u >> 16) & 1u)) >> 16);  // RNE
}

static __device__ __forceinline__ float bf2f(unsigned short u) {
    union { unsigned u; float f; } v; v.u = ((unsigned)u) << 16;
    return v.f;
}

static __device__ __forceinline__ float fast_tanh(float x) {
    float e = __expf(2.0f * x);
    float r = __builtin_amdgcn_rcpf(e + 1.0f);
    return __builtin_fmaf(-2.0f, r, 1.0f);
}

// lgkm-only barrier (R10/R11-verified): orders LDS cross-wave, never drains vmcnt.
static __device__ __forceinline__ void lbar() {
    asm volatile("s_waitcnt lgkmcnt(0)" ::: "memory");
    __builtin_amdgcn_s_barrier();
    __builtin_amdgcn_sched_barrier(0);
}

// 64B-row swizzle: row r, 16B-slot c; byte = r*64 + ((c ^ ((r>>1)&3)) << 4)
static __device__ __forceinline__ unsigned swz64(int r, int c) {
    return (unsigned)(r * 64 + ((c ^ ((r >> 1) & 3)) << 4));
}

// ---------------- projection GEMM body (verified; bf16 output) ----------------
static __device__ void proj_body(
    const float* __restrict__ A, const float* __restrict__ W,
    const float* __restrict__ b, unsigned short* __restrict__ C,
    int mt, int jt, unsigned short* As, unsigned short* Bs)
{
    const int tid = threadIdx.x;
    const int lane = tid & 63, wid = tid >> 6;
    const int wm = wid >> 1, wn = wid & 1;

    f32x4 acc[4][4];
    const f32x4 zero = {0.f, 0.f, 0.f, 0.f};
    #pragma unroll
    for (int i = 0; i < 4; ++i)
        #pragma unroll
        for (int j = 0; j < 4; ++j) acc[i][j] = zero;

    const int c8 = (tid & 7) * 8;
    const int rbase = tid >> 3;

    for (int kt = 0; kt < 8; ++kt) {
        __syncthreads();
        #pragma unroll
        for (int p = 0; p < 4; ++p) {
            int r = p * 32 + rbase;
            int byte = (r * 128 + c8 * 2) ^ ((r & 7) << 4);
            {
                const float* s = A + (size_t)(mt * 128 + r) * 512 + kt * 64 + c8;
                f32x4 v0 = *(const f32x4*)s, v1 = *(const f32x4*)(s + 4);
                s16x8 pk;
                pk[0] = (short)f2bf(v0[0]); pk[1] = (short)f2bf(v0[1]);
                pk[2] = (short)f2bf(v0[2]); pk[3] = (short)f2bf(v0[3]);
                pk[4] = (short)f2bf(v1[0]); pk[5] = (short)f2bf(v1[1]);
                pk[6] = (short)f2bf(v1[2]); pk[7] = (short)f2bf(v1[3]);
                *(s16x8*)((char*)As + byte) = pk;
            }
            {
                const float* s = W + (size_t)(jt * 128 + r) * 512 + kt * 64 + c8;
                f32x4 v0 = *(const f32x4*)s, v1 = *(const f32x4*)(s + 4);
                s16x8 pk;
                pk[0] = (short)f2bf(v0[0]); pk[1] = (short)f2bf(v0[1]);
                pk[2] = (short)f2bf(v0[2]); pk[3] = (short)f2bf(v0[3]);
                pk[4] = (short)f2bf(v1[0]); pk[5] = (short)f2bf(v1[1]);
                pk[6] = (short)f2bf(v1[2]); pk[7] = (short)f2bf(v1[3]);
                *(s16x8*)((char*)Bs + byte) = pk;
            }
        }
        __syncthreads();
        #pragma unroll
        for (int kk = 0; kk < 2; ++kk) {
            s16x8 af[4], bfr[4];
            #pragma unroll
            for (int mi = 0; mi < 4; ++mi) {
                int row = wm * 64 + mi * 16 + (lane & 15);
                int byte = (row * 128 + kk * 64 + ((lane >> 4) * 16)) ^ ((row & 7) << 4);
                af[mi] = *(const s16x8*)((const char*)As + byte);
            }
            #pragma unroll
            for (int ni = 0; ni < 4; ++ni) {
                int row = wn * 64 + ni * 16 + (lane & 15);
                int byte = (row * 128 + kk * 64 + ((lane >> 4) * 16)) ^ ((row & 7) << 4);
                bfr[ni] = *(const s16x8*)((const char*)Bs + byte);
            }
            #pragma unroll
            for (int mi = 0; mi < 4; ++mi)
                #pragma unroll
                for (int ni = 0; ni < 4; ++ni)
                    acc[mi][ni] = __builtin_amdgcn_mfma_f32_16x16x32_bf16(
                        af[mi], bfr[ni], acc[mi][ni], 0, 0, 0);
        }
    }

    #pragma unroll
    for (int ni = 0; ni < 4; ++ni) {
        int col = jt * 128 + wn * 64 + ni * 16 + (lane & 15);
        float bias = b[col];
        #pragma unroll
        for (int mi = 0; mi < 4; ++mi) {
            int row0 = mt * 128 + wm * 64 + mi * 16 + ((lane >> 4) << 2);
            #pragma unroll
            for (int j = 0; j < 4; ++j)
                C[(size_t)(row0 + j) * 512 + col] = f2bf(acc[mi][ni][j] + bias);
        }
    }
}

// ---------------- fused prep: conv_wout | enc proj | dec proj | bpad ----------------
__global__ __launch_bounds__(256) void prep(
    const float* __restrict__ Wout, unsigned short* __restrict__ img,
    const float* __restrict__ encoder_out, const float* __restrict__ W_enc,
    const float* __restrict__ b_enc, unsigned short* __restrict__ enc_p,
    const float* __restrict__ decoder_out, const float* __restrict__ W_dec,
    const float* __restrict__ b_dec, unsigned short* __restrict__ dec_p,
    const float* __restrict__ b_out, float* __restrict__ bpad)
{
    __shared__ unsigned short As[128 * 64];
    __shared__ unsigned short Bs[128 * 64];
    const int b = blockIdx.x;
    if (b < 128) {
        // W_out -> bf16 per-lane MFMA-fragment-ordered image (verified layout):
        // chunk tid = ((kt*16+tile)*2+khalf)*64+lane -> 8 bf16 of
        //   W[v=tile*32+(lane&31)][k=kt*32+khalf*16+(lane>>5)*8 + j], v>=500 -> 0
        int tid = b * 256 + threadIdx.x;
        int lane = tid & 63;
        int khalf = (tid >> 6) & 1;
        int tile = (tid >> 7) & 15;
        int kt = tid >> 11;
        int v = tile * 32 + (lane & 31);
        int k = kt * 32 + khalf * 16 + (lane >> 5) * 8;
        s16x8 pk = {0, 0, 0, 0, 0, 0, 0, 0};
        if (v < 500) {
            const float* s = Wout + (size_t)v * 512 + k;
            f32x4 a = *(const f32x4*)s, c = *(const f32x4*)(s + 4);
            pk[0] = (short)f2bf(a[0]); pk[1] = (short)f2bf(a[1]);
            pk[2] = (short)f2bf(a[2]); pk[3] = (short)f2bf(a[3]);
            pk[4] = (short)f2bf(c[0]); pk[5] = (short)f2bf(c[1]);
            pk[6] = (short)f2bf(c[2]); pk[7] = (short)f2bf(c[3]);
        }
        *(s16x8*)(img + (size_t)tid * 8) = pk;
    } else if (b < 256) {
        int q = b - 128;                       // enc proj: M=4096
        proj_body(encoder_out, W_enc, b_enc, enc_p, q & 31, q >> 5, As, Bs);
    } else if (b < 272) {
        int q = b - 256;                       // dec proj: M=512
        proj_body(decoder_out, W_dec, b_dec, dec_p, q & 3, q >> 2, As, Bs);
    } else {
        int i = threadIdx.x;                   // bpad: 512-padded bias
        bpad[i] = (i < 500) ? b_out[i] : 0.f;
        bpad[i + 256] = (i + 256 < 500) ? b_out[i + 256] : 0.f;
    }
}

// ---------------- fused tanh + vocab GEMM ----------------
__global__ __launch_bounds__(512, 2) void joiner_main(
    const unsigned short* __restrict__ enc, const unsigned short* __restrict__ dec,
    const unsigned short* __restrict__ Wimg, const float* __restrict__ bout,
    float* __restrict__ out)
{
    __shared__ __align__(16) char raw[66048];         // max(A dbuf 16KB, ep [32][516])
    unsigned short* As0 = (unsigned short*)raw;       // 8 KB [128 r][32 k] swizzled
    unsigned short* As1 = (unsigned short*)(raw + 8192);
    float* ep = (float*)raw;                          // aliases A (used after k-loop)

    const int bid = blockIdx.x;                 // bid = n*256 + tt (tt = t-pair)
    const int tid = threadIdx.x, lane = tid & 63, wn = tid >> 6;  // 8 waves across V
    const int n = bid >> 8, tt = bid & 255;

    f32x16 acc[4][2];
    #pragma unroll
    for (int i = 0; i < 4; ++i)
        #pragma unroll
        for (int j = 0; j < 2; ++j)
            #pragma unroll
            for (int e = 0; e < 16; ++e) acc[i][j][e] = 0.f;

    // A staging: thread -> row r = tid>>2 (0..127: t_local = r>>6, u = r&63),
    //            16B chunk q = tid&3 (k = q*8..+7)
    const int r = tid >> 2;
    const int q = tid & 3;
    const int tl = r >> 6, u = r & 63;
    const unsigned short* erow = enc + ((size_t)n * 512 + tt * 2 + tl) * 512 + q * 8;
    const unsigned short* drow = dec + ((size_t)n * 64 + u) * 512 + q * 8;
    const unsigned abyte = swz64(r, q);
    // B fragments: frag-ordered image; wave wn owns v-tiles wn*2+{0,1}
    // layout: kt*32768 + vtile*2048 + khalf*1024 + lane*16
    const char* wbase = (const char*)Wimg + (size_t)wn * 4096 + (size_t)lane * 16;
    const int lr = lane & 31, kg = lane >> 5;

    // ---- prologue: stage A(kt0); prefetch e/d(kt1); load B(kt0) ----
    s16x8 bc0, bc1, bc2, bc3;
    u16x8 eN, dN;
    {
        u16x8 e = *(const u16x8*)erow;
        u16x8 d = *(const u16x8*)drow;
        s16x8 p;
        #pragma unroll
        for (int i = 0; i < 8; ++i)
            p[i] = (short)f2bf(fast_tanh(bf2f(e[i]) + bf2f(d[i])));
        *(s16x8*)((char*)As0 + abyte) = p;
        eN = *(const u16x8*)(erow + 32);
        dN = *(const u16x8*)(drow + 32);
        bc0 = *(const s16x8*)(wbase);
        bc1 = *(const s16x8*)(wbase + 1024);
        bc2 = *(const s16x8*)(wbase + 2048);
        bc3 = *(const s16x8*)(wbase + 3072);
    }
    lbar();

    #pragma unroll
    for (int kt = 0; kt < 16; ++kt) {
        const char* Ac = (char*)((kt & 1) ? As1 : As0);
        char* An = (char*)((kt & 1) ? As0 : As1);

        // 1. stage A(kt+1) from prefetched e/d regs (tanh on VALU pipe)
        if (kt < 15) {
            s16x8 p;
            #pragma unroll
            for (int i = 0; i < 8; ++i)
                p[i] = (short)f2bf(fast_tanh(bf2f(eN[i]) + bf2f(dN[i])));
            *(s16x8*)(An + abyte) = p;
        }
        // 2. prefetch e/d(kt+2)
        if (kt < 14) {
            eN = *(const u16x8*)(erow + (kt + 2) * 32);
            dN = *(const u16x8*)(drow + (kt + 2) * 32);
        }
        // 3. prefetch B(kt+1) into regs
        s16x8 bn0, bn1, bn2, bn3;
        if (kt < 15) {
            const char* g = wbase + (size_t)(kt + 1) * 32768;
            bn0 = *(const s16x8*)(g);
            bn1 = *(const s16x8*)(g + 1024);
            bn2 = *(const s16x8*)(g + 2048);
            bn3 = *(const s16x8*)(g + 3072);
        }
        // 4. kh0: A frags (4 m-subtiles) + 8 MFMAs
        {
            s16x8 a0 = *(const s16x8*)(Ac + swz64(lr, kg));
            s16x8 a1 = *(const s16x8*)(Ac + swz64(32 + lr, kg));
            s16x8 a2 = *(const s16x8*)(Ac + swz64(64 + lr, kg));
            s16x8 a3 = *(const s16x8*)(Ac + swz64(96 + lr, kg));
            acc[0][0] = __builtin_amdgcn_mfma_f32_32x32x16_bf16(bc0, a0, acc[0][0], 0, 0, 0);
            acc[0][1] = __builtin_amdgcn_mfma_f32_32x32x16_bf16(bc2, a0, acc[0][1], 0, 0, 0);
            acc[1][0] = __builtin_amdgcn_mfma_f32_32x32x16_bf16(bc0, a1, acc[1][0], 0, 0, 0);
            acc[1][1] = __builtin_amdgcn_mfma_f32_32x32x16_bf16(bc2, a1, acc[1][1], 0, 0, 0);
            acc[2][0] = __builtin_amdgcn_mfma_f32_32x32x16_bf16(bc0, a2, acc[2][0], 0, 0, 0);
            acc[2][1] = __builtin_amdgcn_mfma_f32_32x32x16_bf16(bc2, a2, acc[2][1], 0, 0, 0);
            acc[3][0] = __builtin_amdgcn_mfma_f32_32x32x16_bf16(bc0, a3, acc[3][0], 0, 0, 0);
            acc[3][1] = __builtin_amdgcn_mfma_f32_32x32x16_bf16(bc2, a3, acc[3][1], 0, 0, 0);
        }
        // 5. kh1
        {
            s16x8 a0 = *(const s16x8*)(Ac + swz64(lr, 2 + kg));
            s16x8 a1 = *(const s16x8*)(Ac + swz64(32 + lr, 2 + kg));
            s16x8 a2 = *(const s16x8*)(Ac + swz64(64 + lr, 2 + kg));
            s16x8 a3 = *(const s16x8*)(Ac + swz64(96 + lr, 2 + kg));
            acc[0][0] = __builtin_amdgcn_mfma_f32_32x32x16_bf16(bc1, a0, acc[0][0], 0, 0, 0);
            acc[0][1] = __builtin_amdgcn_mfma_f32_32x32x16_bf16(bc3, a0, acc[0][1], 0, 0, 0);
            acc[1][0] = __builtin_amdgcn_mfma_f32_32x32x16_bf16(bc1, a1, acc[1][0], 0, 0, 0);
            acc[1][1] = __builtin_amdgcn_mfma_f32_32x32x16_bf16(bc3, a1, acc[1][1], 0, 0, 0);
            acc[2][0] = __builtin_amdgcn_mfma_f32_32x32x16_bf16(bc1, a2, acc[2][0], 0, 0, 0);
            acc[2][1] = __builtin_amdgcn_mfma_f32_32x32x16_bf16(bc3, a2, acc[2][1], 0, 0, 0);
            acc[3][0] = __builtin_amdgcn_mfma_f32_32x32x16_bf16(bc1, a3, acc[3][0], 0, 0, 0);
            acc[3][1] = __builtin_amdgcn_mfma_f32_32x32x16_bf16(bc3, a3, acc[3][1], 0, 0, 0);
        }
        // 6. lgkm-only barrier; B/ed prefetch stays in flight
        lbar();
        bc0 = bn0; bc1 = bn1; bc2 = bn2; bc3 = bn3;
    }

    // ---- epilogue: 4 rounds of 32 rows (round o = acc[o]); LDS transpose ->
    //      linear NT streams. acc[mi][ni][reg]: m = mi*32 + lr,
    //      v = wn*64 + ni*32 + (reg&3) + 8*(reg>>2) + 4*kg
    const int hi4 = kg * 4;
    #pragma unroll
    for (int o = 0; o < 4; ++o) {
        if (o) lbar();                    // round 0 covered by k-loop's final lbar
        {
            #pragma unroll
            for (int ni = 0; ni < 2; ++ni) {
                #pragma unroll
                for (int qq = 0; qq < 4; ++qq) {
                    int v4 = wn * 64 + ni * 32 + qq * 8 + hi4;
                    if (v4 < 500) {
                        f32x4 b = *(const f32x4*)(bout + v4);   // bout 512-padded
                        f32x4 ov;
                        ov[0] = acc[o][ni][qq * 4 + 0] + b[0];
                        ov[1] = acc[o][ni][qq * 4 + 1] + b[1];
                        ov[2] = acc[o][ni][qq * 4 + 2] + b[2];
                        ov[3] = acc[o][ni][qq * 4 + 3] + b[3];
                        *(f32x4*)(ep + lr * 516 + v4) = ov;
                    }
                }
            }
        }
        lbar();
        // rows o*32..o*32+31 of the 128-row tile: t_local = o>>1, u0 = (o&1)*32
        const size_t base =
            (((size_t)n * 512 + tt * 2 + (o >> 1)) * 64 + (o & 1) * 32) * 500;
        #pragma unroll
        for (int i = 0; i < 8; ++i) {
            int idx = i * 512 + tid;                    // f32x4 chunk, 4000 total
            if (idx < 4000) {
                int rr = idx / 125;
                int vi = (idx - rr * 125) * 4;
                f32x4 ov = *(const f32x4*)(ep + rr * 516 + vi);
                __builtin_nontemporal_store(ov, (f32x4*)(out + base + (size_t)idx * 4));
            }
        }
    }
}

extern "C" void kernel_launch(void* const* d_in, const int* in_sizes, int n_in,
                              void* d_out, int out_size, void* d_ws, size_t ws_size,
                              hipStream_t stream) {
    const float* encoder_out = (const float*)d_in[0];  // [8,512,512]
    const float* decoder_out = (const float*)d_in[1];  // [8,64,512]
    const float* W_enc = (const float*)d_in[2];
    const float* b_enc = (const float*)d_in[3];
    const float* W_dec = (const float*)d_in[4];
    const float* b_dec = (const float*)d_in[5];
    const float* W_out = (const float*)d_in[6];        // [500,512]
    const float* b_out = (const float*)d_in[7];        // [500]
    float* out = (float*)d_out;                        // [8,512,64,500]

    unsigned short* enc_p = (unsigned short*)d_ws;              // 4 MB bf16
    unsigned short* dec_p = enc_p + (size_t)4096 * 512;         // 512 KB bf16
    unsigned short* wimg  = dec_p + (size_t)512 * 512;          // 512 KB bf16
    float* bpad = (float*)(wimg + 262144);                      // 2 KB f32

    prep<<<dim3(273), 256, 0, stream>>>(W_out, wimg,
                                        encoder_out, W_enc, b_enc, enc_p,
                                        decoder_out, W_dec, b_dec, dec_p,
                                        b_out, bpad);
    joiner_main<<<dim3(2048), 512, 0, stream>>>(enc_p, dec_p, wimg, bpad, out);
}